// Round 7
// baseline (1920.952 us; speedup 1.0000x reference)
//
#include <hip/hip_runtime.h>
#include <stdint.h>
#include <stddef.h>

typedef unsigned short u16;
typedef unsigned long long u64;

#define NTREES 256
#define NPT 511
#define TD 128

// resolved-pointer table slots
#define S_TOKA 0
#define S_SRTA 1
#define S_CSTA 2
#define S_TOKB 3
#define S_SRTB 4
#define S_CSTB 5
#define S_EMB  6
#define S_SORT 7
#define S_WIOU 8
#define S_BIOU 9
#define S_UIOU 10
#define S_WF   11
#define S_BF   12
#define S_UF   13
#define S_W1   14
#define S_B1   15
#define S_W2   16
#define S_B2   17

// f32 weight-block offsets (elements)
#define O_WIOU 0
#define O_WF   73728
#define O_UIOU 98304
#define O_UF   147456
#define O_BIOU 163840
#define O_BF   164224
#define O_W1   164352
#define O_B1   197248
#define O_W2   197376
#define O_B2   197632
#define W_TOTAL 197634

struct ArgPack { u64 p[32]; int sz[32]; int n; };

static __device__ __forceinline__ float bf2f(u16 x){
  union { unsigned u; float f; } v; v.u = ((unsigned)x) << 16; return v.f;
}
static __device__ __forceinline__ float sigm(float x){ return 1.f/(1.f+expf(-x)); }
static __device__ __forceinline__ float ldin(const void* p, size_t i, int fl){
  return fl ? ((const float*)p)[i] : bf2f(((const u16*)p)[i]);
}
static __device__ __forceinline__ int ldint(const void* p, size_t i, int i64){
  return ((const int*)p)[i << i64];
}

// ------------------------------------------------ input resolver (order-free)
__global__ void resolve_k(ArgPack ap, u64* __restrict__ tab, int* __restrict__ flags){
  if (threadIdx.x != 0 || blockIdx.x != 0) return;
  // dict-order fallback defaults
  if (ap.n >= 24) {
    const int map[18] = {0,1,2,3,4,5,12,13,14,15,16,17,18,19,20,21,22,23};
    for (int s = 0; s < 18; ++s) tab[s] = ap.p[map[s]];
  } else if (ap.n >= 22) {
    const int map[18] = {0,1,2,3,4,5,10,11,12,13,14,15,16,17,18,19,20,21};
    for (int s = 0; s < 18; ++s) tab[s] = ap.p[map[s]];
  }
  int ntok = 0, nsrt = 0, ncst = 0, nb128 = 0;
  int tok_i64 = 0, srt_i64 = 0;
  for (int i = 0; i < ap.n && i < 32; ++i) {
    const int s = ap.sz[i];
    const u64 p = ap.p[i];
    int slot = -1;
    if (s == 8372224)      { slot = ncst ? S_CSTB : S_CSTA; ncst++; }
    else if (s == 130816) {
      const int* q = (const int*)p;
      int nz = 0;
      for (int j = 300; j < 430; ++j) if (q[2 * j + 1] != 0) nz++;
      const int w = (nz == 0) ? 1 : 0;                 // 1 = int64
      long vmax = 0;
      for (int j = 256; j < 768; ++j) { long v = w ? (long)q[2 * j] : (long)q[j]; if (v > vmax) vmax = v; }
      if (vmax <= 16)        slot = -1;                // node_order: unused
      else if (vmax <= 4096) { slot = nsrt ? S_SRTB : S_SRTA; nsrt++; srt_i64 = w; }
      else                   { slot = ntok ? S_TOKB : S_TOKA; ntok++; tok_i64 = w; }
    }
    else if (s == 1280000) slot = S_EMB;
    else if (s == 8192)    slot = S_SORT;
    else if (s == 73728)   slot = S_WIOU;
    else if (s == 384)     slot = S_BIOU;
    else if (s == 49152)   slot = S_UIOU;
    else if (s == 24576)   slot = S_WF;
    else if (s == 128)     { slot = nb128 ? S_B1 : S_BF; nb128++; }  // both all-zero
    else if (s == 16384)   slot = S_UF;
    else if (s == 32896)   slot = S_W1;
    else if (s == 256)     slot = S_W2;
    else if (s == 2)       slot = S_B2;
    if (slot >= 0) tab[slot] = p;
  }
  flags[1] = tok_i64;
  flags[2] = srt_i64;
  // float width probe on emb: low-halves of f32 words look like huge/denormal bf16
  const u16* pu = (const u16*)tab[S_EMB];
  int huge = 0;
  for (int i = 0; i < 1024; ++i) { const float v = fabsf(bf2f(pu[2 * i])); if (v > 1e4f) huge++; }
  flags[0] = (huge > 40) ? 1 : 0;   // 1 = f32, 0 = bf16
}

// ------------------------------------------------ weights -> f32 block
__global__ __launch_bounds__(256) void prep_k(const u64* __restrict__ tab,
    const int* __restrict__ flags, float* __restrict__ wf)
{
  const int fl = flags[0];
  const int tid = blockIdx.x * 256 + threadIdx.x;
  if (tid >= W_TOTAL) return;
  float v;
  if      (tid < O_WF)   v = ldin((const void*)tab[S_WIOU], tid - O_WIOU, fl);
  else if (tid < O_UIOU) v = ldin((const void*)tab[S_WF],   tid - O_WF,   fl);
  else if (tid < O_UF)   v = ldin((const void*)tab[S_UIOU], tid - O_UIOU, fl);
  else if (tid < O_BIOU) v = ldin((const void*)tab[S_UF],   tid - O_UF,   fl);
  else if (tid < O_BF)   v = ldin((const void*)tab[S_BIOU], tid - O_BIOU, fl);
  else if (tid < O_W1)   v = ldin((const void*)tab[S_BF],   tid - O_BF,   fl);
  else if (tid < O_B1)   v = ldin((const void*)tab[S_W1],   tid - O_W1,   fl);
  else if (tid < O_W2)   v = ldin((const void*)tab[S_B1],   tid - O_B1,   fl);
  else if (tid < O_B2)   v = ldin((const void*)tab[S_W2],   tid - O_W2,   fl);
  else                   v = ldin((const void*)tab[S_B2],   tid - O_B2,   fl);
  wf[tid] = v;
}

// ------------------------------------------------ bottom L levels fused, register h/c
template<int L>
__global__ __launch_bounds__(128) void bottom_k(const u64* __restrict__ tab,
    const int* __restrict__ flags, const float* __restrict__ wf,
    float* __restrict__ h, float* __restrict__ c, const int so)
{
  constexpr int G = 16 >> L;
  __shared__ float sfeat[16][192];
  __shared__ float childh[16][128];
  const void* tokens = (const void*)tab[so + 0];
  const void* sorts  = (const void*)tab[so + 1];
  const void* cst    = (const void*)tab[so + 2];
  const void* emb    = (const void*)tab[S_EMB];
  const void* sortt  = (const void*)tab[S_SORT];
  const int d = threadIdx.x;
  const int fl = flags[0], ti = flags[1], si = flags[2];
  const int m0 = blockIdx.x * G;

  const float bi  = wf[O_BIOU + d];
  const float bo  = wf[O_BIOU + 128 + d];
  const float bu  = wf[O_BIOU + 256 + d];
  const float bf_ = wf[O_BF + d];

  for (int idx = d; idx < 16 * 192; idx += 128) {
    const int g = idx / 192, k = idx - g * 192;
    const int gl = (m0 << L) + g;
    const int tree = gl >> 8, j = gl & 255;
    const size_t node = (size_t)tree * NPT + j;
    float v;
    if (k < 64) {
      int tok = ldint(tokens, node, ti); tok = tok < 0 ? 0 : (tok > 19999 ? 19999 : tok);
      v = ldin(emb, (size_t)tok * 64 + k, fl);
    } else if (k < 128) {
      int srt = ldint(sorts, node, si); srt = srt < 0 ? 0 : (srt > 127 ? 127 : srt);
      v = ldin(sortt, (size_t)srt * 64 + (k - 64), fl);
    } else v = ldin(cst, node * 64 + (k - 128), fl);
    sfeat[g][k] = v;
  }
  __syncthreads();

  float hb[16], cb[16];
  {
    float ai[16], ao[16], au[16];
#pragma unroll
    for (int g = 0; g < 16; ++g) { ai[g] = bi; ao[g] = bo; au[g] = bu; }
    for (int k = 0; k < 192; ++k) {
      const float wi = wf[O_WIOU + (size_t)k * 384 + d];
      const float wo = wf[O_WIOU + (size_t)k * 384 + 128 + d];
      const float wu = wf[O_WIOU + (size_t)k * 384 + 256 + d];
#pragma unroll
      for (int g = 0; g < 16; ++g) {
        const float x = sfeat[g][k];
        ai[g] = fmaf(x, wi, ai[g]);
        ao[g] = fmaf(x, wo, ao[g]);
        au[g] = fmaf(x, wu, au[g]);
      }
    }
#pragma unroll
    for (int g = 0; g < 16; ++g) {
      const float cv = sigm(ai[g]) * tanhf(au[g]);
      cb[g] = cv;
      hb[g] = sigm(ao[g]) * tanhf(cv);
    }
  }

#pragma unroll
  for (int lev = 1; lev <= L; ++lev) {
    const int nn = 16 >> lev;
    __syncthreads();
#pragma unroll
    for (int j = 0; j < 32; ++j)
      if (j < 2 * nn) childh[j][d] = hb[j];
    for (int idx = d; idx < nn * 192; idx += 128) {
      const int g = idx / 192, k = idx - g * 192;
      const int gle = (m0 << (L - lev)) + g;
      const int lpt = 8 - lev;
      const int tree = gle >> lpt, j = gle & ((1 << lpt) - 1);
      const size_t node = (size_t)tree * NPT + (512 - (1 << (9 - lev))) + j;
      float v;
      if (k < 64) {
        int tok = ldint(tokens, node, ti); tok = tok < 0 ? 0 : (tok > 19999 ? 19999 : tok);
        v = ldin(emb, (size_t)tok * 64 + k, fl);
      } else if (k < 128) {
        int srt = ldint(sorts, node, si); srt = srt < 0 ? 0 : (srt > 127 ? 127 : srt);
        v = ldin(sortt, (size_t)srt * 64 + (k - 64), fl);
      } else v = ldin(cst, node * 64 + (k - 128), fl);
      sfeat[g][k] = v;
    }
    __syncthreads();

    float ai[8], ao[8], au[8], af[8], f0[8], f1[8];
#pragma unroll
    for (int g = 0; g < 8; ++g) { ai[g] = bi; ao[g] = bo; au[g] = bu; af[g] = bf_; f0[g] = 0.f; f1[g] = 0.f; }
    for (int k = 0; k < 192; ++k) {
      const float wi = wf[O_WIOU + (size_t)k * 384 + d];
      const float wo = wf[O_WIOU + (size_t)k * 384 + 128 + d];
      const float wu = wf[O_WIOU + (size_t)k * 384 + 256 + d];
      const float wfc = wf[O_WF + (size_t)k * 128 + d];
#pragma unroll
      for (int g = 0; g < 8; ++g) {
        if (g < nn) {
          const float x = sfeat[g][k];
          ai[g] = fmaf(x, wi, ai[g]);
          ao[g] = fmaf(x, wo, ao[g]);
          au[g] = fmaf(x, wu, au[g]);
          af[g] = fmaf(x, wfc, af[g]);
        }
      }
    }
    for (int k = 0; k < 128; ++k) {
      const float ui = wf[O_UIOU + (size_t)k * 384 + d];
      const float uo = wf[O_UIOU + (size_t)k * 384 + 128 + d];
      const float uu = wf[O_UIOU + (size_t)k * 384 + 256 + d];
      const float uf = wf[O_UF + (size_t)k * 128 + d];
#pragma unroll
      for (int g = 0; g < 8; ++g) {
        if (g < nn) {
          const float s0 = childh[2 * g][k], s1 = childh[2 * g + 1][k];
          const float s = s0 + s1;
          ai[g] = fmaf(s, ui, ai[g]);
          ao[g] = fmaf(s, uo, ao[g]);
          au[g] = fmaf(s, uu, au[g]);
          f0[g] = fmaf(s0, uf, f0[g]);
          f1[g] = fmaf(s1, uf, f1[g]);
        }
      }
    }
#pragma unroll
    for (int g = 0; g < 8; ++g) {
      if (g < nn) {
        float cn = sigm(ai[g]) * tanhf(au[g])
                 + sigm(af[g] + f0[g]) * cb[2 * g]
                 + sigm(af[g] + f1[g]) * cb[2 * g + 1];
        hb[g] = sigm(ao[g]) * tanhf(cn);
        cb[g] = cn;
      }
    }
  }

#pragma unroll
  for (int g = 0; g < 16; ++g)
    if (g < G) {
      h[((size_t)(m0 + g)) * TD + d] = hb[g];
      c[((size_t)(m0 + g)) * TD + d] = cb[g];
    }
}

// ------------------------------------------------ upper levels, in-place compaction
__global__ __launch_bounds__(128) void level_k(const u64* __restrict__ tab,
    const int* __restrict__ flags, const float* __restrict__ wf,
    float* __restrict__ h, float* __restrict__ c, const int so,
    const int lpt, const int offp, const int tt)
{
  __shared__ float sf[8][192];
  __shared__ float sh0[8][128], sh1[8][128];
  const void* tokens = (const void*)tab[so + 0];
  const void* sorts  = (const void*)tab[so + 1];
  const void* cst    = (const void*)tab[so + 2];
  const void* emb    = (const void*)tab[S_EMB];
  const void* sortt  = (const void*)tab[S_SORT];
  const int d = threadIdx.x;
  const int fl = flags[0], ti = flags[1], si = flags[2];
  const int m0 = blockIdx.x * 8;
  const int mask = (1 << lpt) - 1;

  for (int idx = d; idx < 8 * 192; idx += 128) {
    const int g = idx / 192, k = idx - g * 192;
    const int m = m0 + g;
    const int tree = m >> lpt, j = m & mask;
    const size_t node = (size_t)tree * NPT + offp + j;
    float v;
    if (k < 64) {
      int tok = ldint(tokens, node, ti); tok = tok < 0 ? 0 : (tok > 19999 ? 19999 : tok);
      v = ldin(emb, (size_t)tok * 64 + k, fl);
    } else if (k < 128) {
      int srt = ldint(sorts, node, si); srt = srt < 0 ? 0 : (srt > 127 ? 127 : srt);
      v = ldin(sortt, (size_t)srt * 64 + (k - 64), fl);
    } else v = ldin(cst, node * 64 + (k - 128), fl);
    sf[g][k] = v;
  }
  for (int idx = d; idx < 8 * 128; idx += 128) {
    const int g = idx >> 7, k = idx & 127;
    const size_t s0 = ((size_t)(m0 + g)) << tt;
    const size_t s1 = s0 + ((size_t)1 << (tt - 1));
    sh0[g][k] = h[s0 * TD + k];
    sh1[g][k] = h[s1 * TD + k];
  }
  __syncthreads();

  const float bi  = wf[O_BIOU + d];
  const float bo  = wf[O_BIOU + 128 + d];
  const float bu  = wf[O_BIOU + 256 + d];
  const float bf_ = wf[O_BF + d];

  float ai[8], ao[8], au[8], af[8], f0[8], f1[8];
#pragma unroll
  for (int g = 0; g < 8; ++g) { ai[g] = bi; ao[g] = bo; au[g] = bu; af[g] = bf_; f0[g] = 0.f; f1[g] = 0.f; }

  for (int k = 0; k < 192; ++k) {
    const float wi = wf[O_WIOU + (size_t)k * 384 + d];
    const float wo = wf[O_WIOU + (size_t)k * 384 + 128 + d];
    const float wu = wf[O_WIOU + (size_t)k * 384 + 256 + d];
    const float wfc = wf[O_WF + (size_t)k * 128 + d];
#pragma unroll
    for (int g = 0; g < 8; ++g) {
      const float x = sf[g][k];
      ai[g] = fmaf(x, wi, ai[g]);
      ao[g] = fmaf(x, wo, ao[g]);
      au[g] = fmaf(x, wu, au[g]);
      af[g] = fmaf(x, wfc, af[g]);
    }
  }
  for (int k = 0; k < 128; ++k) {
    const float ui = wf[O_UIOU + (size_t)k * 384 + d];
    const float uo = wf[O_UIOU + (size_t)k * 384 + 128 + d];
    const float uu = wf[O_UIOU + (size_t)k * 384 + 256 + d];
    const float uf = wf[O_UF + (size_t)k * 128 + d];
#pragma unroll
    for (int g = 0; g < 8; ++g) {
      const float s0 = sh0[g][k], s1 = sh1[g][k], s = s0 + s1;
      ai[g] = fmaf(s,  ui, ai[g]);
      ao[g] = fmaf(s,  uo, ao[g]);
      au[g] = fmaf(s,  uu, au[g]);
      f0[g] = fmaf(s0, uf, f0[g]);
      f1[g] = fmaf(s1, uf, f1[g]);
    }
  }
#pragma unroll
  for (int g = 0; g < 8; ++g) {
    const size_t pslot = ((size_t)(m0 + g)) << tt;
    const size_t s1 = pslot + ((size_t)1 << (tt - 1));
    float cn = sigm(ai[g]) * tanhf(au[g])
             + sigm(af[g] + f0[g]) * c[pslot * TD + d]
             + sigm(af[g] + f1[g]) * c[s1 * TD + d];
    c[pslot * TD + d] = cn;
    h[pslot * TD + d] = sigm(ao[g]) * tanhf(cn);
  }
}

// ------------------------------------------------ side-a root copy
__global__ __launch_bounds__(256) void roots_k(const float* __restrict__ h,
                                               float* __restrict__ ha, const int SH){
  const int gid = blockIdx.x * 256 + threadIdx.x;
  const int tree = gid >> 7, d = gid & 127;
  ha[gid] = h[(((size_t)tree) << SH) * TD + d];
}

// ------------------------------------------------ head (OUTPUT IS FLOAT32)
__global__ __launch_bounds__(128) void final_k(const float* __restrict__ ha,
    const float* __restrict__ h, const float* __restrict__ wf,
    const int SH, float* __restrict__ out)
{
  __shared__ float sa[128], sb[128], red[2], r0s[2], r1s[2];
  const int t = blockIdx.x, d = threadIdx.x;
  const float av = ha[t * 128 + d];
  const float bv = h[(((size_t)t) << SH) * TD + d];
  sa[d] = av; sb[d] = bv;
  float pdt = av * bv;
#pragma unroll
  for (int off = 32; off; off >>= 1) pdt += __shfl_down(pdt, off);
  if ((d & 63) == 0) red[d >> 6] = pdt;
  __syncthreads();
  const float dotp = red[0] + red[1];
  float r = wf[O_B1 + d];
  for (int k = 0; k < 128; ++k) r = fmaf(sa[k], wf[O_W1 + (size_t)k * 128 + d], r);
  for (int k = 0; k < 128; ++k) r = fmaf(sb[k], wf[O_W1 + (size_t)(128 + k) * 128 + d], r);
  r = fmaf(dotp, wf[O_W1 + (size_t)256 * 128 + d], r);
  r = fmaxf(r, 0.f);
  float o0 = r * wf[O_W2 + (size_t)d * 2];
  float o1 = r * wf[O_W2 + (size_t)d * 2 + 1];
#pragma unroll
  for (int off = 32; off; off >>= 1) { o0 += __shfl_down(o0, off); o1 += __shfl_down(o1, off); }
  if ((d & 63) == 0) { r0s[d >> 6] = o0; r1s[d >> 6] = o1; }
  __syncthreads();
  if (d == 0) {
    out[t * 2]     = r0s[0] + r0s[1] + wf[O_B2];
    out[t * 2 + 1] = r1s[0] + r1s[1] + wf[O_B2 + 1];
  }
}

// ------------------------------------------------ host
static void run_side(int L, const u64* tab, const int* flags, const float* wf,
                     float* h, float* c, int so, hipStream_t stream)
{
  const int nb = (NTREES << (8 - L)) / (16 >> L);
  switch (L) {
    case 1: bottom_k<1><<<nb, 128, 0, stream>>>(tab, flags, wf, h, c, so); break;
    case 2: bottom_k<2><<<nb, 128, 0, stream>>>(tab, flags, wf, h, c, so); break;
    case 3: bottom_k<3><<<nb, 128, 0, stream>>>(tab, flags, wf, h, c, so); break;
    default: bottom_k<4><<<nb, 128, 0, stream>>>(tab, flags, wf, h, c, so); break;
  }
  for (int t = L + 1; t <= 8; ++t) {
    const int NL = NTREES << (8 - t);
    level_k<<<NL / 8, 128, 0, stream>>>(tab, flags, wf, h, c, so,
        8 - t, 512 - (1 << (9 - t)), t - L);
  }
}

extern "C" void kernel_launch(void* const* d_in, const int* in_sizes, int n_in,
                              void* d_out, int out_size, void* d_ws, size_t ws_size,
                              hipStream_t stream)
{
  ArgPack ap;
  ap.n = n_in < 32 ? n_in : 32;
  for (int i = 0; i < 32; ++i) {
    ap.p[i]  = (i < n_in) ? (u64)d_in[i] : 0ull;
    ap.sz[i] = (i < n_in) ? in_sizes[i] : 0;
  }

  char* p = (char*)d_ws;
  auto take = [&](size_t bytes){ char* q = p; p += (bytes + 255) & ~(size_t)255; return q; };

  u64*   tab   = (u64*)take(18 * 8);
  int*   flags = (int*)take(256);
  float* wfb   = (float*)take((size_t)W_TOTAL * 4);
  float* ha    = (float*)take((size_t)NTREES * TD * 4);
  const size_t fixedB = (size_t)(p - (char*)d_ws);

  int L = 1;
  while (L < 4) {
    const size_t need = fixedB + 2 * (((size_t)(NTREES << (8 - L))) * TD * 4 + 256) + 1024;
    if (ws_size >= need) break;
    ++L;
  }
  const int SH = 8 - L;
  const size_t hcB = ((size_t)(NTREES << SH)) * TD * 4;
  float* h = (float*)take(hcB);
  float* c = (float*)take(hcB);

  resolve_k<<<1, 64, 0, stream>>>(ap, tab, flags);
  prep_k<<<(W_TOTAL + 255) / 256, 256, 0, stream>>>(tab, flags, wfb);

  run_side(L, tab, flags, wfb, h, c, S_TOKA, stream);
  roots_k<<<(NTREES * TD) / 256, 256, 0, stream>>>(h, ha, SH);
  run_side(L, tab, flags, wfb, h, c, S_TOKB, stream);
  final_k<<<NTREES, 128, 0, stream>>>(ha, h, wfb, SH, (float*)d_out);
}

// Round 8
// 1132.879 us; speedup vs baseline: 1.6956x; 1.6956x over previous
//
#include <hip/hip_runtime.h>
#include <stdint.h>
#include <stddef.h>

typedef unsigned short u16;
typedef unsigned long long u64;
typedef short bf16x8 __attribute__((ext_vector_type(8)));
typedef float f32x4 __attribute__((ext_vector_type(4)));

#define NTREES 256
#define NPT 511
#define TD 128

// resolved-pointer table slots
#define S_TOKA 0
#define S_SRTA 1
#define S_CSTA 2
#define S_TOKB 3
#define S_SRTB 4
#define S_CSTB 5
#define S_EMB  6
#define S_SORT 7
#define S_WIOU 8
#define S_BIOU 9
#define S_UIOU 10
#define S_WF   11
#define S_BF   12
#define S_UF   13
#define S_W1   14
#define S_B1   15
#define S_W2   16
#define S_B2   17

// f32 weight-block offsets (elements)
#define O_WIOU 0
#define O_WF   73728
#define O_UIOU 98304
#define O_UF   147456
#define O_BIOU 163840
#define O_BF   164224
#define O_W1   164352
#define O_B1   197248
#define O_W2   197376
#define O_B2   197632
#define W_TOTAL 197634

struct ArgPack { u64 p[32]; int sz[32]; int n; };

static __device__ __forceinline__ float bf2f(u16 x){
  union { unsigned u; float f; } v; v.u = ((unsigned)x) << 16; return v.f;
}
static __device__ __forceinline__ u16 f2bf(float f){
  union { float f; unsigned u; } v; v.f = f;
  unsigned r = v.u + 0x7fffu + ((v.u >> 16) & 1u);
  return (u16)(r >> 16);
}
static __device__ __forceinline__ float sigm(float x){ return 1.f/(1.f+expf(-x)); }
static __device__ __forceinline__ float ldin(const void* p, size_t i, int fl){
  return fl ? ((const float*)p)[i] : bf2f(((const u16*)p)[i]);
}
static __device__ __forceinline__ int ldint(const void* p, size_t i, int i64){
  return ((const int*)p)[i << i64];
}

// ------------------------------------------------ input resolver (order-free)
__global__ void resolve_k(ArgPack ap, u64* __restrict__ tab, int* __restrict__ flags){
  if (threadIdx.x != 0 || blockIdx.x != 0) return;
  if (ap.n >= 24) {
    const int map[18] = {0,1,2,3,4,5,12,13,14,15,16,17,18,19,20,21,22,23};
    for (int s = 0; s < 18; ++s) tab[s] = ap.p[map[s]];
  } else if (ap.n >= 22) {
    const int map[18] = {0,1,2,3,4,5,10,11,12,13,14,15,16,17,18,19,20,21};
    for (int s = 0; s < 18; ++s) tab[s] = ap.p[map[s]];
  }
  int ntok = 0, nsrt = 0, ncst = 0, nb128 = 0;
  int tok_i64 = 0, srt_i64 = 0;
  for (int i = 0; i < ap.n && i < 32; ++i) {
    const int s = ap.sz[i];
    const u64 p = ap.p[i];
    int slot = -1;
    if (s == 8372224)      { slot = ncst ? S_CSTB : S_CSTA; ncst++; }
    else if (s == 130816) {
      const int* q = (const int*)p;
      int nz = 0;
      for (int j = 300; j < 430; ++j) if (q[2 * j + 1] != 0) nz++;
      const int w = (nz == 0) ? 1 : 0;
      long vmax = 0;
      for (int j = 256; j < 768; ++j) { long v = w ? (long)q[2 * j] : (long)q[j]; if (v > vmax) vmax = v; }
      if (vmax <= 16)        slot = -1;
      else if (vmax <= 4096) { slot = nsrt ? S_SRTB : S_SRTA; nsrt++; srt_i64 = w; }
      else                   { slot = ntok ? S_TOKB : S_TOKA; ntok++; tok_i64 = w; }
    }
    else if (s == 1280000) slot = S_EMB;
    else if (s == 8192)    slot = S_SORT;
    else if (s == 73728)   slot = S_WIOU;
    else if (s == 384)     slot = S_BIOU;
    else if (s == 49152)   slot = S_UIOU;
    else if (s == 24576)   slot = S_WF;
    else if (s == 128)     { slot = nb128 ? S_B1 : S_BF; nb128++; }
    else if (s == 16384)   slot = S_UF;
    else if (s == 32896)   slot = S_W1;
    else if (s == 256)     slot = S_W2;
    else if (s == 2)       slot = S_B2;
    if (slot >= 0) tab[slot] = p;
  }
  flags[1] = tok_i64;
  flags[2] = srt_i64;
  const u16* pu = (const u16*)tab[S_EMB];
  int huge = 0;
  for (int i = 0; i < 1024; ++i) { const float v = fabsf(bf2f(pu[2 * i])); if (v > 1e4f) huge++; }
  flags[0] = (huge > 40) ? 1 : 0;
}

// ------------------------------------------------ weights -> f32 block (head + fallback)
__global__ __launch_bounds__(256) void prep_k(const u64* __restrict__ tab,
    const int* __restrict__ flags, float* __restrict__ wf)
{
  const int fl = flags[0];
  const int tid = blockIdx.x * 256 + threadIdx.x;
  if (tid >= W_TOTAL) return;
  float v;
  if      (tid < O_WF)   v = ldin((const void*)tab[S_WIOU], tid - O_WIOU, fl);
  else if (tid < O_UIOU) v = ldin((const void*)tab[S_WF],   tid - O_WF,   fl);
  else if (tid < O_UF)   v = ldin((const void*)tab[S_UIOU], tid - O_UIOU, fl);
  else if (tid < O_BIOU) v = ldin((const void*)tab[S_UF],   tid - O_UF,   fl);
  else if (tid < O_BF)   v = ldin((const void*)tab[S_BIOU], tid - O_BIOU, fl);
  else if (tid < O_W1)   v = ldin((const void*)tab[S_BF],   tid - O_BF,   fl);
  else if (tid < O_B1)   v = ldin((const void*)tab[S_W1],   tid - O_W1,   fl);
  else if (tid < O_W2)   v = ldin((const void*)tab[S_B1],   tid - O_B1,   fl);
  else if (tid < O_B2)   v = ldin((const void*)tab[S_W2],   tid - O_W2,   fl);
  else                   v = ldin((const void*)tab[S_B2],   tid - O_B2,   fl);
  wf[tid] = v;
}

// ------------------------------------------------ combined-weight split-bf16 prep
// WzT[n][k] (n<640, k<448) transposed, hi/lo split. bz[640].
__global__ __launch_bounds__(256) void prep_w(const u64* __restrict__ tab,
    const int* __restrict__ flags, u16* __restrict__ wzhi, u16* __restrict__ wzlo,
    float* __restrict__ bz)
{
  const int fl = flags[0];
  const int tid = blockIdx.x * 256 + threadIdx.x;
  if (tid < 640) {
    bz[tid] = (tid < 384) ? ldin((const void*)tab[S_BIOU], tid, fl)
                          : ldin((const void*)tab[S_BF], (tid - 384) & 127, fl);
  }
  if (tid >= 640 * 448) return;
  const int n = tid / 448, k = tid - n * 448;
  float v;
  if (k < 192) {
    v = (n < 384) ? ldin((const void*)tab[S_WIOU], (size_t)k * 384 + n, fl)
                  : ldin((const void*)tab[S_WF],   (size_t)k * 128 + ((n - 384) & 127), fl);
  } else if (k < 320) {
    const int kk = k - 192;
    v = (n < 384) ? ldin((const void*)tab[S_UIOU], (size_t)kk * 384 + n, fl)
      : (n < 512) ? ldin((const void*)tab[S_UF],   (size_t)kk * 128 + (n - 384), fl) : 0.f;
  } else {
    const int kk = k - 320;
    v = (n < 384) ? ldin((const void*)tab[S_UIOU], (size_t)kk * 384 + n, fl)
      : (n < 512) ? 0.f : ldin((const void*)tab[S_UF], (size_t)kk * 128 + (n - 512), fl);
  }
  const u16 hi = f2bf(v);
  wzhi[(size_t)n * 448 + k] = hi;
  wzlo[(size_t)n * 448 + k] = f2bf(v - bf2f(hi));
}

// ------------------------------------------------ split-bf16 MFMA level kernel
// 64 parents/block, 512 threads (8 waves). Wave w owns col-frag gate*8+w.
// z = [feat(192) | h0(128) | h1(128)]; 3-term split product per k-step.
static __device__ __forceinline__ int mix4(int r){ return (r + (r >> 2)) & 3; }

template<bool LEAF>
__global__ __launch_bounds__(512) void gemm_level_k(
    const u64* __restrict__ tab, const int* __restrict__ flags,
    const u16* __restrict__ wzhi, const u16* __restrict__ wzlo,
    const float* __restrict__ bz,
    float* __restrict__ h, float* __restrict__ c,
    const int T, const int soArg, const int slotMult)
{
  constexpr int NKS  = LEAF ? 6 : 14;
  constexpr int NG   = LEAF ? 3 : 5;
  constexpr int NCOL = LEAF ? 384 : 640;
  constexpr int BIT  = NCOL * 4 / 512;
  __shared__ __align__(16) u16 Ah[64 * 32];
  __shared__ __align__(16) u16 Al[64 * 32];
  __shared__ __align__(16) u16 Bs[NCOL * 32];

  const int so = soArg + 3 * blockIdx.y;
  const size_t slotbase = (size_t)slotMult * blockIdx.y;
  float* hs = h + slotbase * TD;
  float* cs_ = c + slotbase * TD;
  const void* tokens = (const void*)tab[so + 0];
  const void* sorts  = (const void*)tab[so + 1];
  const void* cstp   = (const void*)tab[so + 2];
  const void* emb    = (const void*)tab[S_EMB];
  const void* sortt  = (const void*)tab[S_SORT];
  const int fl = flags[0], ti = flags[1], si = flags[2];
  const int tid = threadIdx.x, l = tid & 63, w = tid >> 6, lr = l & 15, lq = l >> 4;
  const int m0 = blockIdx.x * 64;
  const int lpt = 8 - T, mask = (1 << lpt) - 1, offp = 512 - (1 << (9 - T));

  // A-stage thread ids (first 256 threads)
  const int arow = tid >> 1 >> 1, apart = tid & 3;   // arow = tid>>2
  const int am = m0 + arow;
  const int atree = am >> lpt, aj = am & mask;
  const size_t anode = (size_t)atree * NPT + offp + aj;
  int tok = 0, srt = 0;
  size_t acs0 = 0, acs1 = 0;
  if (tid < 256) {
    tok = ldint(tokens, anode, ti); tok = tok < 0 ? 0 : (tok > 19999 ? 19999 : tok);
    srt = ldint(sorts,  anode, si); srt = srt < 0 ? 0 : (srt > 127 ? 127 : srt);
    if (!LEAF) { acs0 = ((size_t)am) << T; acs1 = acs0 + ((size_t)1 << (T - 1)); }
  }

  f32x4 acc[4][NG];
#pragma unroll
  for (int mf = 0; mf < 4; ++mf)
#pragma unroll
    for (int g = 0; g < NG; ++g) acc[mf][g] = f32x4{0.f, 0.f, 0.f, 0.f};

  for (int ks = 0; ks < NKS; ++ks) {
    const int k0 = ks * 32;
    if (tid < 256) {   // A stage: 64 rows x 32 k, gathered + split
      float xv[8];
      const int kb = k0 + apart * 8;
      if (kb < 64) {
#pragma unroll
        for (int j = 0; j < 8; ++j) xv[j] = ldin(emb, (size_t)tok * 64 + kb + j, fl);
      } else if (kb < 128) {
#pragma unroll
        for (int j = 0; j < 8; ++j) xv[j] = ldin(sortt, (size_t)srt * 64 + (kb - 64) + j, fl);
      } else if (kb < 192) {
#pragma unroll
        for (int j = 0; j < 8; ++j) xv[j] = ldin(cstp, anode * 64 + (kb - 128) + j, fl);
      } else if (kb < 320) {
        const float* hp = hs + acs0 * TD + (kb - 192);
#pragma unroll
        for (int j = 0; j < 8; ++j) xv[j] = hp[j];
      } else {
        const float* hp = hs + acs1 * TD + (kb - 320);
#pragma unroll
        for (int j = 0; j < 8; ++j) xv[j] = hp[j];
      }
      u16 hi8[8], lo8[8];
#pragma unroll
      for (int j = 0; j < 8; ++j) {
        const u16 hh = f2bf(xv[j]);
        hi8[j] = hh;
        lo8[j] = f2bf(xv[j] - bf2f(hh));
      }
      const int aoff = arow * 32 + ((apart ^ mix4(arow)) << 3);
      *(uint4*)&Ah[aoff] = *(const uint4*)hi8;
      *(uint4*)&Al[aoff] = *(const uint4*)lo8;
    }
#pragma unroll
    for (int i = 0; i < BIT; ++i) {   // B-hi stage
      const int flat = tid + i * 512, col = flat >> 2, q = flat & 3;
      *(uint4*)&Bs[col * 32 + ((q ^ mix4(col)) << 3)] =
          *(const uint4*)&wzhi[(size_t)col * 448 + k0 + q * 8];
    }
    __syncthreads();
    bf16x8 ah[4], al[4];
#pragma unroll
    for (int mf = 0; mf < 4; ++mf) {
      const int row = mf * 16 + lr;
      const int off = row * 32 + ((lq ^ mix4(row)) << 3);
      ah[mf] = *(const bf16x8*)&Ah[off];
      al[mf] = *(const bf16x8*)&Al[off];
    }
#pragma unroll
    for (int g = 0; g < NG; ++g) {
      const int bcol = (g * 8 + w) * 16 + lr;
      const bf16x8 bb = *(const bf16x8*)&Bs[bcol * 32 + ((lq ^ mix4(bcol)) << 3)];
#pragma unroll
      for (int mf = 0; mf < 4; ++mf) {
        acc[mf][g] = __builtin_amdgcn_mfma_f32_16x16x32_bf16(ah[mf], bb, acc[mf][g], 0, 0, 0);
        acc[mf][g] = __builtin_amdgcn_mfma_f32_16x16x32_bf16(al[mf], bb, acc[mf][g], 0, 0, 0);
      }
    }
    __syncthreads();
#pragma unroll
    for (int i = 0; i < BIT; ++i) {   // B-lo stage (same buffer)
      const int flat = tid + i * 512, col = flat >> 2, q = flat & 3;
      *(uint4*)&Bs[col * 32 + ((q ^ mix4(col)) << 3)] =
          *(const uint4*)&wzlo[(size_t)col * 448 + k0 + q * 8];
    }
    __syncthreads();
#pragma unroll
    for (int g = 0; g < NG; ++g) {
      const int bcol = (g * 8 + w) * 16 + lr;
      const bf16x8 bb = *(const bf16x8*)&Bs[bcol * 32 + ((lq ^ mix4(bcol)) << 3)];
#pragma unroll
      for (int mf = 0; mf < 4; ++mf)
        acc[mf][g] = __builtin_amdgcn_mfma_f32_16x16x32_bf16(ah[mf], bb, acc[mf][g], 0, 0, 0);
    }
    __syncthreads();
  }

  // epilogue: wave w owns d = w*16 + lr for all 64 rows
  const int d = w * 16 + lr;
  const float bi = bz[d], bo = bz[128 + d], bu = bz[256 + d];
  float bf0 = 0.f, bf1 = 0.f;
  if (!LEAF) { bf0 = bz[384 + d]; bf1 = bz[512 + d]; }
#pragma unroll
  for (int mf = 0; mf < 4; ++mf) {
#pragma unroll
    for (int rr = 0; rr < 4; ++rr) {
      const int row = mf * 16 + lq * 4 + rr;
      const int m = m0 + row;
      const size_t ps = LEAF ? (size_t)m : (((size_t)m) << T);
      const float iv = acc[mf][0][rr] + bi;
      const float ov = acc[mf][1][rr] + bo;
      const float uv = acc[mf][2][rr] + bu;
      float cn = sigm(iv) * tanhf(uv);
      if (!LEAF) {
        const size_t c1s = ps + ((size_t)1 << (T - 1));
        cn += sigm(acc[mf][3][rr] + bf0) * cs_[ps * TD + d]
            + sigm(acc[mf][4][rr] + bf1) * cs_[c1s * TD + d];
      }
      cs_[ps * TD + d] = cn;
      hs[ps * TD + d] = sigm(ov) * tanhf(cn);
    }
  }
}

// ------------------------------------------------ fallback: round-7 VALU kernels
template<int L>
__global__ __launch_bounds__(128) void bottom_k(const u64* __restrict__ tab,
    const int* __restrict__ flags, const float* __restrict__ wf,
    float* __restrict__ h, float* __restrict__ c, const int so)
{
  constexpr int G = 16 >> L;
  __shared__ float sfeat[16][192];
  __shared__ float childh[16][128];
  const void* tokens = (const void*)tab[so + 0];
  const void* sorts  = (const void*)tab[so + 1];
  const void* cst    = (const void*)tab[so + 2];
  const void* emb    = (const void*)tab[S_EMB];
  const void* sortt  = (const void*)tab[S_SORT];
  const int d = threadIdx.x;
  const int fl = flags[0], ti = flags[1], si = flags[2];
  const int m0 = blockIdx.x * G;

  const float bi  = wf[O_BIOU + d];
  const float bo  = wf[O_BIOU + 128 + d];
  const float bu  = wf[O_BIOU + 256 + d];
  const float bf_ = wf[O_BF + d];

  for (int idx = d; idx < 16 * 192; idx += 128) {
    const int g = idx / 192, k = idx - g * 192;
    const int gl = (m0 << L) + g;
    const int tree = gl >> 8, j = gl & 255;
    const size_t node = (size_t)tree * NPT + j;
    float v;
    if (k < 64) {
      int tk = ldint(tokens, node, ti); tk = tk < 0 ? 0 : (tk > 19999 ? 19999 : tk);
      v = ldin(emb, (size_t)tk * 64 + k, fl);
    } else if (k < 128) {
      int sr = ldint(sorts, node, si); sr = sr < 0 ? 0 : (sr > 127 ? 127 : sr);
      v = ldin(sortt, (size_t)sr * 64 + (k - 64), fl);
    } else v = ldin(cst, node * 64 + (k - 128), fl);
    sfeat[g][k] = v;
  }
  __syncthreads();

  float hb[16], cb[16];
  {
    float ai[16], ao[16], au[16];
#pragma unroll
    for (int g = 0; g < 16; ++g) { ai[g] = bi; ao[g] = bo; au[g] = bu; }
    for (int k = 0; k < 192; ++k) {
      const float wi = wf[O_WIOU + (size_t)k * 384 + d];
      const float wo = wf[O_WIOU + (size_t)k * 384 + 128 + d];
      const float wu = wf[O_WIOU + (size_t)k * 384 + 256 + d];
#pragma unroll
      for (int g = 0; g < 16; ++g) {
        const float x = sfeat[g][k];
        ai[g] = fmaf(x, wi, ai[g]);
        ao[g] = fmaf(x, wo, ao[g]);
        au[g] = fmaf(x, wu, au[g]);
      }
    }
#pragma unroll
    for (int g = 0; g < 16; ++g) {
      const float cv = sigm(ai[g]) * tanhf(au[g]);
      cb[g] = cv;
      hb[g] = sigm(ao[g]) * tanhf(cv);
    }
  }

#pragma unroll
  for (int lev = 1; lev <= L; ++lev) {
    const int nn = 16 >> lev;
    __syncthreads();
#pragma unroll
    for (int j = 0; j < 32; ++j)
      if (j < 2 * nn) childh[j][d] = hb[j];
    for (int idx = d; idx < nn * 192; idx += 128) {
      const int g = idx / 192, k = idx - g * 192;
      const int gle = (m0 << (L - lev)) + g;
      const int lpt = 8 - lev;
      const int tree = gle >> lpt, j = gle & ((1 << lpt) - 1);
      const size_t node = (size_t)tree * NPT + (512 - (1 << (9 - lev))) + j;
      float v;
      if (k < 64) {
        int tk = ldint(tokens, node, ti); tk = tk < 0 ? 0 : (tk > 19999 ? 19999 : tk);
        v = ldin(emb, (size_t)tk * 64 + k, fl);
      } else if (k < 128) {
        int sr = ldint(sorts, node, si); sr = sr < 0 ? 0 : (sr > 127 ? 127 : sr);
        v = ldin(sortt, (size_t)sr * 64 + (k - 64), fl);
      } else v = ldin(cst, node * 64 + (k - 128), fl);
      sfeat[g][k] = v;
    }
    __syncthreads();

    float ai[8], ao[8], au[8], af[8], f0[8], f1[8];
#pragma unroll
    for (int g = 0; g < 8; ++g) { ai[g] = bi; ao[g] = bo; au[g] = bu; af[g] = bf_; f0[g] = 0.f; f1[g] = 0.f; }
    for (int k = 0; k < 192; ++k) {
      const float wi = wf[O_WIOU + (size_t)k * 384 + d];
      const float wo = wf[O_WIOU + (size_t)k * 384 + 128 + d];
      const float wu = wf[O_WIOU + (size_t)k * 384 + 256 + d];
      const float wfc = wf[O_WF + (size_t)k * 128 + d];
#pragma unroll
      for (int g = 0; g < 8; ++g) {
        if (g < nn) {
          const float x = sfeat[g][k];
          ai[g] = fmaf(x, wi, ai[g]);
          ao[g] = fmaf(x, wo, ao[g]);
          au[g] = fmaf(x, wu, au[g]);
          af[g] = fmaf(x, wfc, af[g]);
        }
      }
    }
    for (int k = 0; k < 128; ++k) {
      const float ui = wf[O_UIOU + (size_t)k * 384 + d];
      const float uo = wf[O_UIOU + (size_t)k * 384 + 128 + d];
      const float uu = wf[O_UIOU + (size_t)k * 384 + 256 + d];
      const float uf = wf[O_UF + (size_t)k * 128 + d];
#pragma unroll
      for (int g = 0; g < 8; ++g) {
        if (g < nn) {
          const float s0 = childh[2 * g][k], s1 = childh[2 * g + 1][k];
          const float s = s0 + s1;
          ai[g] = fmaf(s, ui, ai[g]);
          ao[g] = fmaf(s, uo, ao[g]);
          au[g] = fmaf(s, uu, au[g]);
          f0[g] = fmaf(s0, uf, f0[g]);
          f1[g] = fmaf(s1, uf, f1[g]);
        }
      }
    }
#pragma unroll
    for (int g = 0; g < 8; ++g) {
      if (g < nn) {
        float cn = sigm(ai[g]) * tanhf(au[g])
                 + sigm(af[g] + f0[g]) * cb[2 * g]
                 + sigm(af[g] + f1[g]) * cb[2 * g + 1];
        hb[g] = sigm(ao[g]) * tanhf(cn);
        cb[g] = cn;
      }
    }
  }

#pragma unroll
  for (int g = 0; g < 16; ++g)
    if (g < G) {
      h[((size_t)(m0 + g)) * TD + d] = hb[g];
      c[((size_t)(m0 + g)) * TD + d] = cb[g];
    }
}

__global__ __launch_bounds__(128) void level_k(const u64* __restrict__ tab,
    const int* __restrict__ flags, const float* __restrict__ wf,
    float* __restrict__ h, float* __restrict__ c, const int so,
    const int lpt, const int offp, const int tt)
{
  __shared__ float sf[8][192];
  __shared__ float sh0[8][128], sh1[8][128];
  const void* tokens = (const void*)tab[so + 0];
  const void* sorts  = (const void*)tab[so + 1];
  const void* cst    = (const void*)tab[so + 2];
  const void* emb    = (const void*)tab[S_EMB];
  const void* sortt  = (const void*)tab[S_SORT];
  const int d = threadIdx.x;
  const int fl = flags[0], ti = flags[1], si = flags[2];
  const int m0 = blockIdx.x * 8;
  const int mask = (1 << lpt) - 1;

  for (int idx = d; idx < 8 * 192; idx += 128) {
    const int g = idx / 192, k = idx - g * 192;
    const int m = m0 + g;
    const int tree = m >> lpt, j = m & mask;
    const size_t node = (size_t)tree * NPT + offp + j;
    float v;
    if (k < 64) {
      int tk = ldint(tokens, node, ti); tk = tk < 0 ? 0 : (tk > 19999 ? 19999 : tk);
      v = ldin(emb, (size_t)tk * 64 + k, fl);
    } else if (k < 128) {
      int sr = ldint(sorts, node, si); sr = sr < 0 ? 0 : (sr > 127 ? 127 : sr);
      v = ldin(sortt, (size_t)sr * 64 + (k - 64), fl);
    } else v = ldin(cst, node * 64 + (k - 128), fl);
    sf[g][k] = v;
  }
  for (int idx = d; idx < 8 * 128; idx += 128) {
    const int g = idx >> 7, k = idx & 127;
    const size_t s0 = ((size_t)(m0 + g)) << tt;
    const size_t s1 = s0 + ((size_t)1 << (tt - 1));
    sh0[g][k] = h[s0 * TD + k];
    sh1[g][k] = h[s1 * TD + k];
  }
  __syncthreads();

  const float bi  = wf[O_BIOU + d];
  const float bo  = wf[O_BIOU + 128 + d];
  const float bu  = wf[O_BIOU + 256 + d];
  const float bf_ = wf[O_BF + d];

  float ai[8], ao[8], au[8], af[8], f0[8], f1[8];
#pragma unroll
  for (int g = 0; g < 8; ++g) { ai[g] = bi; ao[g] = bo; au[g] = bu; af[g] = bf_; f0[g] = 0.f; f1[g] = 0.f; }

  for (int k = 0; k < 192; ++k) {
    const float wi = wf[O_WIOU + (size_t)k * 384 + d];
    const float wo = wf[O_WIOU + (size_t)k * 384 + 128 + d];
    const float wu = wf[O_WIOU + (size_t)k * 384 + 256 + d];
    const float wfc = wf[O_WF + (size_t)k * 128 + d];
#pragma unroll
    for (int g = 0; g < 8; ++g) {
      const float x = sf[g][k];
      ai[g] = fmaf(x, wi, ai[g]);
      ao[g] = fmaf(x, wo, ao[g]);
      au[g] = fmaf(x, wu, au[g]);
      af[g] = fmaf(x, wfc, af[g]);
    }
  }
  for (int k = 0; k < 128; ++k) {
    const float ui = wf[O_UIOU + (size_t)k * 384 + d];
    const float uo = wf[O_UIOU + (size_t)k * 384 + 128 + d];
    const float uu = wf[O_UIOU + (size_t)k * 384 + 256 + d];
    const float uf = wf[O_UF + (size_t)k * 128 + d];
#pragma unroll
    for (int g = 0; g < 8; ++g) {
      const float s0 = sh0[g][k], s1 = sh1[g][k], s = s0 + s1;
      ai[g] = fmaf(s,  ui, ai[g]);
      ao[g] = fmaf(s,  uo, ao[g]);
      au[g] = fmaf(s,  uu, au[g]);
      f0[g] = fmaf(s0, uf, f0[g]);
      f1[g] = fmaf(s1, uf, f1[g]);
    }
  }
#pragma unroll
  for (int g = 0; g < 8; ++g) {
    const size_t pslot = ((size_t)(m0 + g)) << tt;
    const size_t s1 = pslot + ((size_t)1 << (tt - 1));
    float cn = sigm(ai[g]) * tanhf(au[g])
             + sigm(af[g] + f0[g]) * c[pslot * TD + d]
             + sigm(af[g] + f1[g]) * c[s1 * TD + d];
    c[pslot * TD + d] = cn;
    h[pslot * TD + d] = sigm(ao[g]) * tanhf(cn);
  }
}

// ------------------------------------------------ roots / head
__global__ __launch_bounds__(256) void roots_k(const float* __restrict__ h,
                                               float* __restrict__ ha, const int SH){
  const int gid = blockIdx.x * 256 + threadIdx.x;
  const int tree = gid >> 7, d = gid & 127;
  ha[gid] = h[(((size_t)tree) << SH) * TD + d];
}

__global__ __launch_bounds__(128) void final_k(const float* __restrict__ ha,
    const float* __restrict__ h, const float* __restrict__ wf,
    const long rb, const int SH, float* __restrict__ out)
{
  __shared__ float sa[128], sb[128], red[2], r0s[2], r1s[2];
  const int t = blockIdx.x, d = threadIdx.x;
  const float av = ha[t * 128 + d];
  const float bv = h[((size_t)rb + (((size_t)t) << SH)) * TD + d];
  sa[d] = av; sb[d] = bv;
  float pdt = av * bv;
#pragma unroll
  for (int off = 32; off; off >>= 1) pdt += __shfl_down(pdt, off);
  if ((d & 63) == 0) red[d >> 6] = pdt;
  __syncthreads();
  const float dotp = red[0] + red[1];
  float r = wf[O_B1 + d];
  for (int k = 0; k < 128; ++k) r = fmaf(sa[k], wf[O_W1 + (size_t)k * 128 + d], r);
  for (int k = 0; k < 128; ++k) r = fmaf(sb[k], wf[O_W1 + (size_t)(128 + k) * 128 + d], r);
  r = fmaf(dotp, wf[O_W1 + (size_t)256 * 128 + d], r);
  r = fmaxf(r, 0.f);
  float o0 = r * wf[O_W2 + (size_t)d * 2];
  float o1 = r * wf[O_W2 + (size_t)d * 2 + 1];
#pragma unroll
  for (int off = 32; off; off >>= 1) { o0 += __shfl_down(o0, off); o1 += __shfl_down(o1, off); }
  if ((d & 63) == 0) { r0s[d >> 6] = o0; r1s[d >> 6] = o1; }
  __syncthreads();
  if (d == 0) {
    out[t * 2]     = r0s[0] + r0s[1] + wf[O_B2];
    out[t * 2 + 1] = r1s[0] + r1s[1] + wf[O_B2 + 1];
  }
}

// ------------------------------------------------ host
static void run_gemm_levels(const u64* tab, const int* flags, const u16* wzhi,
                            const u16* wzlo, const float* bz, float* h, float* c,
                            int soArg, int slotMult, int nsides, hipStream_t stream)
{
  gemm_level_k<true><<<dim3(1024, nsides), 512, 0, stream>>>(
      tab, flags, wzhi, wzlo, bz, h, c, 0, soArg, slotMult);
  for (int T = 1; T <= 8; ++T) {
    const int blocks = (NTREES << (8 - T)) / 64;
    gemm_level_k<false><<<dim3(blocks, nsides), 512, 0, stream>>>(
        tab, flags, wzhi, wzlo, bz, h, c, T, soArg, slotMult);
  }
}

static void run_side_valu(int L, const u64* tab, const int* flags, const float* wf,
                          float* h, float* c, int so, hipStream_t stream)
{
  const int nb = (NTREES << (8 - L)) / (16 >> L);
  switch (L) {
    case 1: bottom_k<1><<<nb, 128, 0, stream>>>(tab, flags, wf, h, c, so); break;
    case 2: bottom_k<2><<<nb, 128, 0, stream>>>(tab, flags, wf, h, c, so); break;
    case 3: bottom_k<3><<<nb, 128, 0, stream>>>(tab, flags, wf, h, c, so); break;
    default: bottom_k<4><<<nb, 128, 0, stream>>>(tab, flags, wf, h, c, so); break;
  }
  for (int t = L + 1; t <= 8; ++t) {
    const int NL = NTREES << (8 - t);
    level_k<<<NL / 8, 128, 0, stream>>>(tab, flags, wf, h, c, so,
        8 - t, 512 - (1 << (9 - t)), t - L);
  }
}

extern "C" void kernel_launch(void* const* d_in, const int* in_sizes, int n_in,
                              void* d_out, int out_size, void* d_ws, size_t ws_size,
                              hipStream_t stream)
{
  ArgPack ap;
  ap.n = n_in < 32 ? n_in : 32;
  for (int i = 0; i < 32; ++i) {
    ap.p[i]  = (i < n_in) ? (u64)d_in[i] : 0ull;
    ap.sz[i] = (i < n_in) ? in_sizes[i] : 0;
  }

  char* p = (char*)d_ws;
  auto take = [&](size_t bytes){ char* q = p; p += (bytes + 255) & ~(size_t)255; return q; };

  u64*   tab   = (u64*)take(18 * 8);
  int*   flags = (int*)take(256);
  float* wfb   = (float*)take((size_t)W_TOTAL * 4);
  u16*   wzhi  = (u16*)take((size_t)640 * 448 * 2);
  u16*   wzlo  = (u16*)take((size_t)640 * 448 * 2);
  float* bz    = (float*)take(640 * 4);
  float* ha    = (float*)take((size_t)NTREES * TD * 4);
  const size_t fixedB = (size_t)(p - (char*)d_ws);

  const size_t slotB = (size_t)65536 * TD * 4;           // 33.55 MB per h/c per side
  const size_t need_conc = fixedB + 4 * slotB + (1 << 16);
  const size_t need_seq  = fixedB + 2 * slotB + (1 << 16);

  resolve_k<<<1, 64, 0, stream>>>(ap, tab, flags);
  prep_k<<<(W_TOTAL + 255) / 256, 256, 0, stream>>>(tab, flags, wfb);

  if (ws_size >= need_seq) {
    prep_w<<<(640 * 448 + 255) / 256, 256, 0, stream>>>(tab, flags, wzhi, wzlo, bz);
    if (ws_size >= need_conc) {
      float* h = (float*)take(2 * slotB);
      float* c = (float*)take(2 * slotB);
      run_gemm_levels(tab, flags, wzhi, wzlo, bz, h, c, S_TOKA, 65536, 2, stream);
      roots_k<<<(NTREES * TD) / 256, 256, 0, stream>>>(h, ha, 8);
      final_k<<<NTREES, 128, 0, stream>>>(ha, h, wfb, 65536L, 8, (float*)d_out);
    } else {
      float* h = (float*)take(slotB);
      float* c = (float*)take(slotB);
      run_gemm_levels(tab, flags, wzhi, wzlo, bz, h, c, S_TOKA, 0, 1, stream);
      roots_k<<<(NTREES * TD) / 256, 256, 0, stream>>>(h, ha, 8);
      run_gemm_levels(tab, flags, wzhi, wzlo, bz, h, c, S_TOKB, 0, 1, stream);
      final_k<<<NTREES, 128, 0, stream>>>(ha, h, wfb, 0L, 8, (float*)d_out);
    }
    return;
  }

  // fallback: round-7 verified VALU pipeline
  int L = 1;
  while (L < 4) {
    const size_t need = fixedB + 2 * (((size_t)(NTREES << (8 - L))) * TD * 4 + 256) + 1024;
    if (ws_size >= need) break;
    ++L;
  }
  const int SH = 8 - L;
  const size_t hcB = ((size_t)(NTREES << SH)) * TD * 4;
  float* h = (float*)take(hcB);
  float* c = (float*)take(hcB);
  run_side_valu(L, tab, flags, wfb, h, c, S_TOKA, stream);
  roots_k<<<(NTREES * TD) / 256, 256, 0, stream>>>(h, ha, SH);
  run_side_valu(L, tab, flags, wfb, h, c, S_TOKB, stream);
  final_k<<<NTREES, 128, 0, stream>>>(ha, h, wfb, 0L, SH, (float*)d_out);
}

// Round 9
// 878.144 us; speedup vs baseline: 2.1875x; 1.2901x over previous
//
#include <hip/hip_runtime.h>
#include <stdint.h>
#include <stddef.h>

typedef unsigned short u16;
typedef unsigned long long u64;
typedef short bf16x8 __attribute__((ext_vector_type(8)));
typedef float f32x4 __attribute__((ext_vector_type(4)));

#define NTREES 256
#define NPT 511
#define TD 128
#define PLANE_E ((size_t)65536 * TD)   // h/c elements per side

// resolved-pointer table slots
#define S_TOKA 0
#define S_SRTA 1
#define S_CSTA 2
#define S_TOKB 3
#define S_SRTB 4
#define S_CSTB 5
#define S_EMB  6
#define S_SORT 7
#define S_WIOU 8
#define S_BIOU 9
#define S_UIOU 10
#define S_WF   11
#define S_BF   12
#define S_UF   13
#define S_W1   14
#define S_B1   15
#define S_W2   16
#define S_B2   17

// f32 weight-block offsets (elements)
#define O_WIOU 0
#define O_WF   73728
#define O_UIOU 98304
#define O_UF   147456
#define O_BIOU 163840
#define O_BF   164224
#define O_W1   164352
#define O_B1   197248
#define O_W2   197376
#define O_B2   197632
#define W_TOTAL 197634

struct ArgPack { u64 p[32]; int sz[32]; int n; };

static __device__ __forceinline__ float bf2f(u16 x){
  union { unsigned u; float f; } v; v.u = ((unsigned)x) << 16; return v.f;
}
static __device__ __forceinline__ u16 f2bf(float f){
  union { float f; unsigned u; } v; v.f = f;
  unsigned r = v.u + 0x7fffu + ((v.u >> 16) & 1u);
  return (u16)(r >> 16);
}
static __device__ __forceinline__ float sigm(float x){ return 1.f/(1.f+expf(-x)); }
static __device__ __forceinline__ float ldin(const void* p, size_t i, int fl){
  return fl ? ((const float*)p)[i] : bf2f(((const u16*)p)[i]);
}
static __device__ __forceinline__ int ldint(const void* p, size_t i, int i64){
  return ((const int*)p)[i << i64];
}

// ------------------------------------------------ input resolver (order-free)
__global__ void resolve_k(ArgPack ap, u64* __restrict__ tab, int* __restrict__ flags){
  if (threadIdx.x != 0 || blockIdx.x != 0) return;
  if (ap.n >= 24) {
    const int map[18] = {0,1,2,3,4,5,12,13,14,15,16,17,18,19,20,21,22,23};
    for (int s = 0; s < 18; ++s) tab[s] = ap.p[map[s]];
  } else if (ap.n >= 22) {
    const int map[18] = {0,1,2,3,4,5,10,11,12,13,14,15,16,17,18,19,20,21};
    for (int s = 0; s < 18; ++s) tab[s] = ap.p[map[s]];
  }
  int ntok = 0, nsrt = 0, ncst = 0, nb128 = 0;
  int tok_i64 = 0, srt_i64 = 0;
  for (int i = 0; i < ap.n && i < 32; ++i) {
    const int s = ap.sz[i];
    const u64 p = ap.p[i];
    int slot = -1;
    if (s == 8372224)      { slot = ncst ? S_CSTB : S_CSTA; ncst++; }
    else if (s == 130816) {
      const int* q = (const int*)p;
      int nz = 0;
      for (int j = 300; j < 430; ++j) if (q[2 * j + 1] != 0) nz++;
      const int w = (nz == 0) ? 1 : 0;
      long vmax = 0;
      for (int j = 256; j < 768; ++j) { long v = w ? (long)q[2 * j] : (long)q[j]; if (v > vmax) vmax = v; }
      if (vmax <= 16)        slot = -1;
      else if (vmax <= 4096) { slot = nsrt ? S_SRTB : S_SRTA; nsrt++; srt_i64 = w; }
      else                   { slot = ntok ? S_TOKB : S_TOKA; ntok++; tok_i64 = w; }
    }
    else if (s == 1280000) slot = S_EMB;
    else if (s == 8192)    slot = S_SORT;
    else if (s == 73728)   slot = S_WIOU;
    else if (s == 384)     slot = S_BIOU;
    else if (s == 49152)   slot = S_UIOU;
    else if (s == 24576)   slot = S_WF;
    else if (s == 128)     { slot = nb128 ? S_B1 : S_BF; nb128++; }
    else if (s == 16384)   slot = S_UF;
    else if (s == 32896)   slot = S_W1;
    else if (s == 256)     slot = S_W2;
    else if (s == 2)       slot = S_B2;
    if (slot >= 0) tab[slot] = p;
  }
  flags[1] = tok_i64;
  flags[2] = srt_i64;
  const u16* pu = (const u16*)tab[S_EMB];
  int huge = 0;
  for (int i = 0; i < 1024; ++i) { const float v = fabsf(bf2f(pu[2 * i])); if (v > 1e4f) huge++; }
  flags[0] = (huge > 40) ? 1 : 0;
}

// ------------------------------------------------ weights -> f32 block (head + fallback)
__global__ __launch_bounds__(256) void prep_k(const u64* __restrict__ tab,
    const int* __restrict__ flags, float* __restrict__ wf)
{
  const int fl = flags[0];
  const int tid = blockIdx.x * 256 + threadIdx.x;
  if (tid >= W_TOTAL) return;
  float v;
  if      (tid < O_WF)   v = ldin((const void*)tab[S_WIOU], tid - O_WIOU, fl);
  else if (tid < O_UIOU) v = ldin((const void*)tab[S_WF],   tid - O_WF,   fl);
  else if (tid < O_UF)   v = ldin((const void*)tab[S_UIOU], tid - O_UIOU, fl);
  else if (tid < O_BIOU) v = ldin((const void*)tab[S_UF],   tid - O_UF,   fl);
  else if (tid < O_BF)   v = ldin((const void*)tab[S_BIOU], tid - O_BIOU, fl);
  else if (tid < O_W1)   v = ldin((const void*)tab[S_BF],   tid - O_BF,   fl);
  else if (tid < O_B1)   v = ldin((const void*)tab[S_W1],   tid - O_W1,   fl);
  else if (tid < O_W2)   v = ldin((const void*)tab[S_B1],   tid - O_B1,   fl);
  else if (tid < O_B2)   v = ldin((const void*)tab[S_W2],   tid - O_W2,   fl);
  else                   v = ldin((const void*)tab[S_B2],   tid - O_B2,   fl);
  wf[tid] = v;
}

// ------------------------------------------------ combined-weight split-bf16 prep
// WzT[n][k] (n<640, k<448) transposed, hi/lo split. bz[640].
__global__ __launch_bounds__(256) void prep_w(const u64* __restrict__ tab,
    const int* __restrict__ flags, u16* __restrict__ wzhi, u16* __restrict__ wzlo,
    float* __restrict__ bz)
{
  const int fl = flags[0];
  const int tid = blockIdx.x * 256 + threadIdx.x;
  if (tid < 640) {
    bz[tid] = (tid < 384) ? ldin((const void*)tab[S_BIOU], tid, fl)
                          : ldin((const void*)tab[S_BF], (tid - 384) & 127, fl);
  }
  if (tid >= 640 * 448) return;
  const int n = tid / 448, k = tid - n * 448;
  float v;
  if (k < 192) {
    v = (n < 384) ? ldin((const void*)tab[S_WIOU], (size_t)k * 384 + n, fl)
                  : ldin((const void*)tab[S_WF],   (size_t)k * 128 + ((n - 384) & 127), fl);
  } else if (k < 320) {
    const int kk = k - 192;
    v = (n < 384) ? ldin((const void*)tab[S_UIOU], (size_t)kk * 384 + n, fl)
      : (n < 512) ? ldin((const void*)tab[S_UF],   (size_t)kk * 128 + (n - 384), fl) : 0.f;
  } else {
    const int kk = k - 320;
    v = (n < 384) ? ldin((const void*)tab[S_UIOU], (size_t)kk * 384 + n, fl)
      : (n < 512) ? 0.f : ldin((const void*)tab[S_UF], (size_t)kk * 128 + (n - 512), fl);
  }
  const u16 hi = f2bf(v);
  wzhi[(size_t)n * 448 + k] = hi;
  wzlo[(size_t)n * 448 + k] = f2bf(v - bf2f(hi));
}

// ------------------------------------------------ split-bf16 MFMA level kernel, v2
// 64 parents/block, 512 threads (8 waves). Wave w owns col-frag g*8+w (gate g).
// B read straight from global (L2-resident); A double-buffered in LDS; 1 barrier/k-step.
// h stored as bf16 hi/lo planes; c stays f32.
template<bool LEAF>
__global__ __launch_bounds__(512) void gemm_level_k(
    const u64* __restrict__ tab, const int* __restrict__ flags,
    const u16* __restrict__ wzhi, const u16* __restrict__ wzlo,
    const float* __restrict__ bz,
    u16* __restrict__ hhi, u16* __restrict__ hlo, float* __restrict__ cc,
    const int T, const int soArg, const int slotPerSide)
{
  constexpr int NKS = LEAF ? 6 : 14;
  constexpr int NG  = LEAF ? 3 : 5;
  __shared__ __align__(16) u16 Ah[2][4][64][8];
  __shared__ __align__(16) u16 Al[2][4][64][8];

  const int so = soArg + 3 * blockIdx.y;
  const size_t sb = (size_t)slotPerSide * blockIdx.y * TD;
  u16* hps = hhi + sb;
  u16* lps = hlo + sb;
  float* cps = cc + sb;
  const void* tokens = (const void*)tab[so + 0];
  const void* sorts  = (const void*)tab[so + 1];
  const void* cstp   = (const void*)tab[so + 2];
  const void* emb    = (const void*)tab[S_EMB];
  const void* sortt  = (const void*)tab[S_SORT];
  const int fl = flags[0], ti = flags[1], si = flags[2];
  const int tid = threadIdx.x, l = tid & 63, w = tid >> 6, lr = l & 15, lq = l >> 4;
  const int m0 = blockIdx.x * 64;
  const int lpt = 8 - T, mask = (1 << lpt) - 1, offp = 512 - (1 << (9 - T));

  // stage ids: thread t handles row t&63, k-quad t>>6 (4 consecutive k)
  const int srow = tid & 63, skq = tid >> 6;
  const int sm = m0 + srow;
  const int stree = sm >> lpt, sj = sm & mask;
  const size_t snode = (size_t)stree * NPT + offp + sj;
  int tok = ldint(tokens, snode, ti); tok = tok < 0 ? 0 : (tok > 19999 ? 19999 : tok);
  int srt = ldint(sorts,  snode, si); srt = srt < 0 ? 0 : (srt > 127 ? 127 : srt);
  size_t sc0 = 0, sc1 = 0;
  if (!LEAF) { sc0 = ((size_t)sm) << T; sc1 = sc0 + ((size_t)1 << (T - 1)); }

  auto stage = [&](int ks, int buf) {
    const int kg = ks * 32 + skq * 4;
    u16 hi4[4], lo4[4];
    if (LEAF || kg < 192) {
      if (fl) {
        const float* src;
        if (kg < 64)       src = (const float*)emb   + (size_t)tok * 64 + kg;
        else if (kg < 128) src = (const float*)sortt + (size_t)srt * 64 + (kg - 64);
        else               src = (const float*)cstp  + snode * 64 + (kg - 128);
        const float4 v = *(const float4*)src;
        const float xv[4] = {v.x, v.y, v.z, v.w};
#pragma unroll
        for (int j = 0; j < 4; ++j) {
          hi4[j] = f2bf(xv[j]);
          lo4[j] = f2bf(xv[j] - bf2f(hi4[j]));
        }
      } else {
        const u16* src;
        if (kg < 64)       src = (const u16*)emb   + (size_t)tok * 64 + kg;
        else if (kg < 128) src = (const u16*)sortt + (size_t)srt * 64 + (kg - 64);
        else               src = (const u16*)cstp  + snode * 64 + (kg - 128);
#pragma unroll
        for (int j = 0; j < 4; ++j) { hi4[j] = src[j]; lo4[j] = 0; }
      }
    } else {
      const size_t cslot = (kg < 320) ? sc0 : sc1;
      const int off = (kg < 320) ? (kg - 192) : (kg - 320);
      *(uint2*)hi4 = *(const uint2*)(hps + cslot * TD + off);
      *(uint2*)lo4 = *(const uint2*)(lps + cslot * TD + off);
    }
    *(uint2*)&Ah[buf][skq >> 1][srow][(skq & 1) * 4] = *(const uint2*)hi4;
    *(uint2*)&Al[buf][skq >> 1][srow][(skq & 1) * 4] = *(const uint2*)lo4;
  };

  f32x4 acc[4][NG];
#pragma unroll
  for (int mf = 0; mf < 4; ++mf)
#pragma unroll
    for (int g = 0; g < NG; ++g) acc[mf][g] = f32x4{0.f, 0.f, 0.f, 0.f};

  stage(0, 0);
  for (int ks = 0; ks < NKS; ++ks) {
    __syncthreads();
    if (ks + 1 < NKS) stage(ks + 1, (ks + 1) & 1);
    const int k0 = ks * 32;
    const int buf = ks & 1;
    bf16x8 ah[4], al[4];
#pragma unroll
    for (int mf = 0; mf < 4; ++mf) {
      ah[mf] = *(const bf16x8*)&Ah[buf][lq][mf * 16 + lr][0];
      al[mf] = *(const bf16x8*)&Al[buf][lq][mf * 16 + lr][0];
    }
#pragma unroll
    for (int g = 0; g < NG; ++g) {
      if (!LEAF) {   // skip structurally-zero W blocks (f0 x h1, f1 x h0)
        if (g == 3 && k0 >= 320) continue;
        if (g == 4 && k0 >= 192 && k0 < 320) continue;
      }
      const size_t boff = (size_t)((g * 8 + w) * 16 + lr) * 448 + k0 + lq * 8;
      const bf16x8 bh = *(const bf16x8*)&wzhi[boff];
      const bf16x8 bl = *(const bf16x8*)&wzlo[boff];
#pragma unroll
      for (int mf = 0; mf < 4; ++mf) {
        acc[mf][g] = __builtin_amdgcn_mfma_f32_16x16x32_bf16(ah[mf], bh, acc[mf][g], 0, 0, 0);
        acc[mf][g] = __builtin_amdgcn_mfma_f32_16x16x32_bf16(al[mf], bh, acc[mf][g], 0, 0, 0);
        acc[mf][g] = __builtin_amdgcn_mfma_f32_16x16x32_bf16(ah[mf], bl, acc[mf][g], 0, 0, 0);
      }
    }
  }

  // epilogue: wave w owns d = w*16 + lr for all 64 rows
  const int d = w * 16 + lr;
  const float bi = bz[d], bo = bz[128 + d], bu = bz[256 + d];
  float bf0 = 0.f, bf1 = 0.f;
  if (!LEAF) { bf0 = bz[384 + d]; bf1 = bz[512 + d]; }
#pragma unroll
  for (int mf = 0; mf < 4; ++mf) {
#pragma unroll
    for (int rr = 0; rr < 4; ++rr) {
      const int row = mf * 16 + lq * 4 + rr;
      const int m = m0 + row;
      const size_t ps = LEAF ? (size_t)m : (((size_t)m) << T);
      const float iv = acc[mf][0][rr] + bi;
      const float ov = acc[mf][1][rr] + bo;
      const float uv = acc[mf][2][rr] + bu;
      float cn = sigm(iv) * tanhf(uv);
      if (!LEAF) {
        const size_t c1s = ps + ((size_t)1 << (T - 1));
        cn += sigm(acc[mf][3][rr] + bf0) * cps[ps * TD + d]
            + sigm(acc[mf][4][rr] + bf1) * cps[c1s * TD + d];
      }
      cps[ps * TD + d] = cn;
      const float hv = sigm(ov) * tanhf(cn);
      const u16 hh = f2bf(hv);
      hps[ps * TD + d] = hh;
      lps[ps * TD + d] = f2bf(hv - bf2f(hh));
    }
  }
}

// ------------------------------------------------ fallback: round-7 VALU kernels
template<int L>
__global__ __launch_bounds__(128) void bottom_k(const u64* __restrict__ tab,
    const int* __restrict__ flags, const float* __restrict__ wf,
    float* __restrict__ h, float* __restrict__ c, const int so)
{
  constexpr int G = 16 >> L;
  __shared__ float sfeat[16][192];
  __shared__ float childh[16][128];
  const void* tokens = (const void*)tab[so + 0];
  const void* sorts  = (const void*)tab[so + 1];
  const void* cst    = (const void*)tab[so + 2];
  const void* emb    = (const void*)tab[S_EMB];
  const void* sortt  = (const void*)tab[S_SORT];
  const int d = threadIdx.x;
  const int fl = flags[0], ti = flags[1], si = flags[2];
  const int m0 = blockIdx.x * G;

  const float bi  = wf[O_BIOU + d];
  const float bo  = wf[O_BIOU + 128 + d];
  const float bu  = wf[O_BIOU + 256 + d];
  const float bf_ = wf[O_BF + d];

  for (int idx = d; idx < 16 * 192; idx += 128) {
    const int g = idx / 192, k = idx - g * 192;
    const int gl = (m0 << L) + g;
    const int tree = gl >> 8, j = gl & 255;
    const size_t node = (size_t)tree * NPT + j;
    float v;
    if (k < 64) {
      int tk = ldint(tokens, node, ti); tk = tk < 0 ? 0 : (tk > 19999 ? 19999 : tk);
      v = ldin(emb, (size_t)tk * 64 + k, fl);
    } else if (k < 128) {
      int sr = ldint(sorts, node, si); sr = sr < 0 ? 0 : (sr > 127 ? 127 : sr);
      v = ldin(sortt, (size_t)sr * 64 + (k - 64), fl);
    } else v = ldin(cst, node * 64 + (k - 128), fl);
    sfeat[g][k] = v;
  }
  __syncthreads();

  float hb[16], cb[16];
  {
    float ai[16], ao[16], au[16];
#pragma unroll
    for (int g = 0; g < 16; ++g) { ai[g] = bi; ao[g] = bo; au[g] = bu; }
    for (int k = 0; k < 192; ++k) {
      const float wi = wf[O_WIOU + (size_t)k * 384 + d];
      const float wo = wf[O_WIOU + (size_t)k * 384 + 128 + d];
      const float wu = wf[O_WIOU + (size_t)k * 384 + 256 + d];
#pragma unroll
      for (int g = 0; g < 16; ++g) {
        const float x = sfeat[g][k];
        ai[g] = fmaf(x, wi, ai[g]);
        ao[g] = fmaf(x, wo, ao[g]);
        au[g] = fmaf(x, wu, au[g]);
      }
    }
#pragma unroll
    for (int g = 0; g < 16; ++g) {
      const float cv = sigm(ai[g]) * tanhf(au[g]);
      cb[g] = cv;
      hb[g] = sigm(ao[g]) * tanhf(cv);
    }
  }

#pragma unroll
  for (int lev = 1; lev <= L; ++lev) {
    const int nn = 16 >> lev;
    __syncthreads();
#pragma unroll
    for (int j = 0; j < 32; ++j)
      if (j < 2 * nn) childh[j][d] = hb[j];
    for (int idx = d; idx < nn * 192; idx += 128) {
      const int g = idx / 192, k = idx - g * 192;
      const int gle = (m0 << (L - lev)) + g;
      const int lpt = 8 - lev;
      const int tree = gle >> lpt, j = gle & ((1 << lpt) - 1);
      const size_t node = (size_t)tree * NPT + (512 - (1 << (9 - lev))) + j;
      float v;
      if (k < 64) {
        int tk = ldint(tokens, node, ti); tk = tk < 0 ? 0 : (tk > 19999 ? 19999 : tk);
        v = ldin(emb, (size_t)tk * 64 + k, fl);
      } else if (k < 128) {
        int sr = ldint(sorts, node, si); sr = sr < 0 ? 0 : (sr > 127 ? 127 : sr);
        v = ldin(sortt, (size_t)sr * 64 + (k - 64), fl);
      } else v = ldin(cst, node * 64 + (k - 128), fl);
      sfeat[g][k] = v;
    }
    __syncthreads();

    float ai[8], ao[8], au[8], af[8], f0[8], f1[8];
#pragma unroll
    for (int g = 0; g < 8; ++g) { ai[g] = bi; ao[g] = bo; au[g] = bu; af[g] = bf_; f0[g] = 0.f; f1[g] = 0.f; }
    for (int k = 0; k < 192; ++k) {
      const float wi = wf[O_WIOU + (size_t)k * 384 + d];
      const float wo = wf[O_WIOU + (size_t)k * 384 + 128 + d];
      const float wu = wf[O_WIOU + (size_t)k * 384 + 256 + d];
      const float wfc = wf[O_WF + (size_t)k * 128 + d];
#pragma unroll
      for (int g = 0; g < 8; ++g) {
        if (g < nn) {
          const float x = sfeat[g][k];
          ai[g] = fmaf(x, wi, ai[g]);
          ao[g] = fmaf(x, wo, ao[g]);
          au[g] = fmaf(x, wu, au[g]);
          af[g] = fmaf(x, wfc, af[g]);
        }
      }
    }
    for (int k = 0; k < 128; ++k) {
      const float ui = wf[O_UIOU + (size_t)k * 384 + d];
      const float uo = wf[O_UIOU + (size_t)k * 384 + 128 + d];
      const float uu = wf[O_UIOU + (size_t)k * 384 + 256 + d];
      const float uf = wf[O_UF + (size_t)k * 128 + d];
#pragma unroll
      for (int g = 0; g < 8; ++g) {
        if (g < nn) {
          const float s0 = childh[2 * g][k], s1 = childh[2 * g + 1][k];
          const float s = s0 + s1;
          ai[g] = fmaf(s, ui, ai[g]);
          ao[g] = fmaf(s, uo, ao[g]);
          au[g] = fmaf(s, uu, au[g]);
          f0[g] = fmaf(s0, uf, f0[g]);
          f1[g] = fmaf(s1, uf, f1[g]);
        }
      }
    }
#pragma unroll
    for (int g = 0; g < 8; ++g) {
      if (g < nn) {
        float cn = sigm(ai[g]) * tanhf(au[g])
                 + sigm(af[g] + f0[g]) * cb[2 * g]
                 + sigm(af[g] + f1[g]) * cb[2 * g + 1];
        hb[g] = sigm(ao[g]) * tanhf(cn);
        cb[g] = cn;
      }
    }
  }

#pragma unroll
  for (int g = 0; g < 16; ++g)
    if (g < G) {
      h[((size_t)(m0 + g)) * TD + d] = hb[g];
      c[((size_t)(m0 + g)) * TD + d] = cb[g];
    }
}

__global__ __launch_bounds__(128) void level_k(const u64* __restrict__ tab,
    const int* __restrict__ flags, const float* __restrict__ wf,
    float* __restrict__ h, float* __restrict__ c, const int so,
    const int lpt, const int offp, const int tt)
{
  __shared__ float sf[8][192];
  __shared__ float sh0[8][128], sh1[8][128];
  const void* tokens = (const void*)tab[so + 0];
  const void* sorts  = (const void*)tab[so + 1];
  const void* cst    = (const void*)tab[so + 2];
  const void* emb    = (const void*)tab[S_EMB];
  const void* sortt  = (const void*)tab[S_SORT];
  const int d = threadIdx.x;
  const int fl = flags[0], ti = flags[1], si = flags[2];
  const int m0 = blockIdx.x * 8;
  const int mask = (1 << lpt) - 1;

  for (int idx = d; idx < 8 * 192; idx += 128) {
    const int g = idx / 192, k = idx - g * 192;
    const int m = m0 + g;
    const int tree = m >> lpt, j = m & mask;
    const size_t node = (size_t)tree * NPT + offp + j;
    float v;
    if (k < 64) {
      int tk = ldint(tokens, node, ti); tk = tk < 0 ? 0 : (tk > 19999 ? 19999 : tk);
      v = ldin(emb, (size_t)tk * 64 + k, fl);
    } else if (k < 128) {
      int sr = ldint(sorts, node, si); sr = sr < 0 ? 0 : (sr > 127 ? 127 : sr);
      v = ldin(sortt, (size_t)sr * 64 + (k - 64), fl);
    } else v = ldin(cst, node * 64 + (k - 128), fl);
    sf[g][k] = v;
  }
  for (int idx = d; idx < 8 * 128; idx += 128) {
    const int g = idx >> 7, k = idx & 127;
    const size_t s0 = ((size_t)(m0 + g)) << tt;
    const size_t s1 = s0 + ((size_t)1 << (tt - 1));
    sh0[g][k] = h[s0 * TD + k];
    sh1[g][k] = h[s1 * TD + k];
  }
  __syncthreads();

  const float bi  = wf[O_BIOU + d];
  const float bo  = wf[O_BIOU + 128 + d];
  const float bu  = wf[O_BIOU + 256 + d];
  const float bf_ = wf[O_BF + d];

  float ai[8], ao[8], au[8], af[8], f0[8], f1[8];
#pragma unroll
  for (int g = 0; g < 8; ++g) { ai[g] = bi; ao[g] = bo; au[g] = bu; af[g] = bf_; f0[g] = 0.f; f1[g] = 0.f; }

  for (int k = 0; k < 192; ++k) {
    const float wi = wf[O_WIOU + (size_t)k * 384 + d];
    const float wo = wf[O_WIOU + (size_t)k * 384 + 128 + d];
    const float wu = wf[O_WIOU + (size_t)k * 384 + 256 + d];
    const float wfc = wf[O_WF + (size_t)k * 128 + d];
#pragma unroll
    for (int g = 0; g < 8; ++g) {
      const float x = sf[g][k];
      ai[g] = fmaf(x, wi, ai[g]);
      ao[g] = fmaf(x, wo, ao[g]);
      au[g] = fmaf(x, wu, au[g]);
      af[g] = fmaf(x, wfc, af[g]);
    }
  }
  for (int k = 0; k < 128; ++k) {
    const float ui = wf[O_UIOU + (size_t)k * 384 + d];
    const float uo = wf[O_UIOU + (size_t)k * 384 + 128 + d];
    const float uu = wf[O_UIOU + (size_t)k * 384 + 256 + d];
    const float uf = wf[O_UF + (size_t)k * 128 + d];
#pragma unroll
    for (int g = 0; g < 8; ++g) {
      const float s0 = sh0[g][k], s1 = sh1[g][k], s = s0 + s1;
      ai[g] = fmaf(s,  ui, ai[g]);
      ao[g] = fmaf(s,  uo, ao[g]);
      au[g] = fmaf(s,  uu, au[g]);
      f0[g] = fmaf(s0, uf, f0[g]);
      f1[g] = fmaf(s1, uf, f1[g]);
    }
  }
#pragma unroll
  for (int g = 0; g < 8; ++g) {
    const size_t pslot = ((size_t)(m0 + g)) << tt;
    const size_t s1 = pslot + ((size_t)1 << (tt - 1));
    float cn = sigm(ai[g]) * tanhf(au[g])
             + sigm(af[g] + f0[g]) * c[pslot * TD + d]
             + sigm(af[g] + f1[g]) * c[s1 * TD + d];
    c[pslot * TD + d] = cn;
    h[pslot * TD + d] = sigm(ao[g]) * tanhf(cn);
  }
}

// ------------------------------------------------ roots / head
__global__ __launch_bounds__(256) void roots_k(const float* __restrict__ h,
                                               float* __restrict__ ha, const int SH){
  const int gid = blockIdx.x * 256 + threadIdx.x;
  const int tree = gid >> 7, d = gid & 127;
  ha[gid] = h[(((size_t)tree) << SH) * TD + d];
}

__global__ __launch_bounds__(256) void roots_split(const u16* __restrict__ hhi,
    const u16* __restrict__ hlo, float* __restrict__ ha){
  const int gid = blockIdx.x * 256 + threadIdx.x;
  const int tree = gid >> 7, d = gid & 127;
  const size_t idx = (((size_t)tree) << 8) * TD + d;
  ha[gid] = bf2f(hhi[idx]) + bf2f(hlo[idx]);
}

__global__ __launch_bounds__(128) void final_k(const float* __restrict__ ha,
    const float* __restrict__ h, const float* __restrict__ wf,
    const long rb, const int SH, float* __restrict__ out)
{
  __shared__ float sa[128], sb[128], red[2], r0s[2], r1s[2];
  const int t = blockIdx.x, d = threadIdx.x;
  const float av = ha[t * 128 + d];
  const float bv = h[((size_t)rb + (((size_t)t) << SH)) * TD + d];
  sa[d] = av; sb[d] = bv;
  float pdt = av * bv;
#pragma unroll
  for (int off = 32; off; off >>= 1) pdt += __shfl_down(pdt, off);
  if ((d & 63) == 0) red[d >> 6] = pdt;
  __syncthreads();
  const float dotp = red[0] + red[1];
  float r = wf[O_B1 + d];
  for (int k = 0; k < 128; ++k) r = fmaf(sa[k], wf[O_W1 + (size_t)k * 128 + d], r);
  for (int k = 0; k < 128; ++k) r = fmaf(sb[k], wf[O_W1 + (size_t)(128 + k) * 128 + d], r);
  r = fmaf(dotp, wf[O_W1 + (size_t)256 * 128 + d], r);
  r = fmaxf(r, 0.f);
  float o0 = r * wf[O_W2 + (size_t)d * 2];
  float o1 = r * wf[O_W2 + (size_t)d * 2 + 1];
#pragma unroll
  for (int off = 32; off; off >>= 1) { o0 += __shfl_down(o0, off); o1 += __shfl_down(o1, off); }
  if ((d & 63) == 0) { r0s[d >> 6] = o0; r1s[d >> 6] = o1; }
  __syncthreads();
  if (d == 0) {
    out[t * 2]     = r0s[0] + r0s[1] + wf[O_B2];
    out[t * 2 + 1] = r1s[0] + r1s[1] + wf[O_B2 + 1];
  }
}

__global__ __launch_bounds__(128) void final_split(const float* __restrict__ ha,
    const u16* __restrict__ hhi, const u16* __restrict__ hlo,
    const float* __restrict__ wf, const u64 rb, float* __restrict__ out)
{
  __shared__ float sa[128], sb[128], red[2], r0s[2], r1s[2];
  const int t = blockIdx.x, d = threadIdx.x;
  const float av = ha[t * 128 + d];
  const size_t idx = rb + (((size_t)t) << 8) * TD + d;
  const float bv = bf2f(hhi[idx]) + bf2f(hlo[idx]);
  sa[d] = av; sb[d] = bv;
  float pdt = av * bv;
#pragma unroll
  for (int off = 32; off; off >>= 1) pdt += __shfl_down(pdt, off);
  if ((d & 63) == 0) red[d >> 6] = pdt;
  __syncthreads();
  const float dotp = red[0] + red[1];
  float r = wf[O_B1 + d];
  for (int k = 0; k < 128; ++k) r = fmaf(sa[k], wf[O_W1 + (size_t)k * 128 + d], r);
  for (int k = 0; k < 128; ++k) r = fmaf(sb[k], wf[O_W1 + (size_t)(128 + k) * 128 + d], r);
  r = fmaf(dotp, wf[O_W1 + (size_t)256 * 128 + d], r);
  r = fmaxf(r, 0.f);
  float o0 = r * wf[O_W2 + (size_t)d * 2];
  float o1 = r * wf[O_W2 + (size_t)d * 2 + 1];
#pragma unroll
  for (int off = 32; off; off >>= 1) { o0 += __shfl_down(o0, off); o1 += __shfl_down(o1, off); }
  if ((d & 63) == 0) { r0s[d >> 6] = o0; r1s[d >> 6] = o1; }
  __syncthreads();
  if (d == 0) {
    out[t * 2]     = r0s[0] + r0s[1] + wf[O_B2];
    out[t * 2 + 1] = r1s[0] + r1s[1] + wf[O_B2 + 1];
  }
}

// ------------------------------------------------ host
static void run_gemm_levels(const u64* tab, const int* flags, const u16* wzhi,
                            const u16* wzlo, const float* bz,
                            u16* hhi, u16* hlo, float* cc,
                            int soArg, int slotPerSide, int nsides, hipStream_t stream)
{
  gemm_level_k<true><<<dim3(1024, nsides), 512, 0, stream>>>(
      tab, flags, wzhi, wzlo, bz, hhi, hlo, cc, 0, soArg, slotPerSide);
  for (int T = 1; T <= 8; ++T) {
    const int blocks = (NTREES << (8 - T)) / 64;
    gemm_level_k<false><<<dim3(blocks, nsides), 512, 0, stream>>>(
        tab, flags, wzhi, wzlo, bz, hhi, hlo, cc, T, soArg, slotPerSide);
  }
}

static void run_side_valu(int L, const u64* tab, const int* flags, const float* wf,
                          float* h, float* c, int so, hipStream_t stream)
{
  const int nb = (NTREES << (8 - L)) / (16 >> L);
  switch (L) {
    case 1: bottom_k<1><<<nb, 128, 0, stream>>>(tab, flags, wf, h, c, so); break;
    case 2: bottom_k<2><<<nb, 128, 0, stream>>>(tab, flags, wf, h, c, so); break;
    case 3: bottom_k<3><<<nb, 128, 0, stream>>>(tab, flags, wf, h, c, so); break;
    default: bottom_k<4><<<nb, 128, 0, stream>>>(tab, flags, wf, h, c, so); break;
  }
  for (int t = L + 1; t <= 8; ++t) {
    const int NL = NTREES << (8 - t);
    level_k<<<NL / 8, 128, 0, stream>>>(tab, flags, wf, h, c, so,
        8 - t, 512 - (1 << (9 - t)), t - L);
  }
}

extern "C" void kernel_launch(void* const* d_in, const int* in_sizes, int n_in,
                              void* d_out, int out_size, void* d_ws, size_t ws_size,
                              hipStream_t stream)
{
  ArgPack ap;
  ap.n = n_in < 32 ? n_in : 32;
  for (int i = 0; i < 32; ++i) {
    ap.p[i]  = (i < n_in) ? (u64)d_in[i] : 0ull;
    ap.sz[i] = (i < n_in) ? in_sizes[i] : 0;
  }

  char* p = (char*)d_ws;
  auto take = [&](size_t bytes){ char* q = p; p += (bytes + 255) & ~(size_t)255; return q; };

  u64*   tab   = (u64*)take(18 * 8);
  int*   flags = (int*)take(256);
  float* wfb   = (float*)take((size_t)W_TOTAL * 4);
  u16*   wzhi  = (u16*)take((size_t)640 * 448 * 2);
  u16*   wzlo  = (u16*)take((size_t)640 * 448 * 2);
  float* bz    = (float*)take(640 * 4);
  float* ha    = (float*)take((size_t)NTREES * TD * 4);
  const size_t fixedB = (size_t)(p - (char*)d_ws);

  const size_t sideB = PLANE_E * (2 + 2 + 4);           // hhi+hlo+c per side = 67.1 MB
  const size_t need_conc = fixedB + 2 * sideB + (1 << 16);
  const size_t need_seq  = fixedB + 1 * sideB + (1 << 16);

  resolve_k<<<1, 64, 0, stream>>>(ap, tab, flags);
  prep_k<<<(W_TOTAL + 255) / 256, 256, 0, stream>>>(tab, flags, wfb);

  if (ws_size >= need_seq) {
    prep_w<<<(640 * 448 + 255) / 256, 256, 0, stream>>>(tab, flags, wzhi, wzlo, bz);
    const int nsides = (ws_size >= need_conc) ? 2 : 1;
    u16*   hhi = (u16*)take((size_t)nsides * PLANE_E * 2);
    u16*   hlo = (u16*)take((size_t)nsides * PLANE_E * 2);
    float* cc  = (float*)take((size_t)nsides * PLANE_E * 4);
    if (nsides == 2) {
      run_gemm_levels(tab, flags, wzhi, wzlo, bz, hhi, hlo, cc, S_TOKA, 65536, 2, stream);
      roots_split<<<(NTREES * TD) / 256, 256, 0, stream>>>(hhi, hlo, ha);
      final_split<<<NTREES, 128, 0, stream>>>(ha, hhi, hlo, wfb, (u64)PLANE_E, (float*)d_out);
    } else {
      run_gemm_levels(tab, flags, wzhi, wzlo, bz, hhi, hlo, cc, S_TOKA, 0, 1, stream);
      roots_split<<<(NTREES * TD) / 256, 256, 0, stream>>>(hhi, hlo, ha);
      run_gemm_levels(tab, flags, wzhi, wzlo, bz, hhi, hlo, cc, S_TOKB, 0, 1, stream);
      final_split<<<NTREES, 128, 0, stream>>>(ha, hhi, hlo, wfb, 0ull, (float*)d_out);
    }
    return;
  }

  // fallback: round-7 verified VALU pipeline
  int L = 1;
  while (L < 4) {
    const size_t need = fixedB + 2 * (((size_t)(NTREES << (8 - L))) * TD * 4 + 256) + 1024;
    if (ws_size >= need) break;
    ++L;
  }
  const int SH = 8 - L;
  const size_t hcB = ((size_t)(NTREES << SH)) * TD * 4;
  float* h = (float*)take(hcB);
  float* c = (float*)take(hcB);
  run_side_valu(L, tab, flags, wfb, h, c, S_TOKA, stream);
  roots_k<<<(NTREES * TD) / 256, 256, 0, stream>>>(h, ha, SH);
  run_side_valu(L, tab, flags, wfb, h, c, S_TOKB, stream);
  final_k<<<NTREES, 128, 0, stream>>>(ha, h, wfb, 0L, SH, (float*)d_out);
}